// Round 2
// baseline (165.806 us; speedup 1.0000x reference)
//
#include <hip/hip_runtime.h>
#include <hip/hip_bf16.h>

// Attention_6828998000803 on MI355X (gfx950)
// H=W=64, C=128, HEADS=4, DIM_HEAD=32, HW=4096, SCALE=10, EPS=1e-8
//
// Pipeline: memset(sumsq) -> qkv GEMM (bf16 MFMA, + sumsq atomics)
//           -> flash attention (bf16 MFMA, online softmax)
//           -> output projection (bf16 MFMA) + bias

typedef float  f32x4 __attribute__((ext_vector_type(4)));
typedef short  s16x8 __attribute__((ext_vector_type(8)));
typedef unsigned int   u32x4 __attribute__((ext_vector_type(4)));
typedef unsigned short u16x4 __attribute__((ext_vector_type(4)));
typedef unsigned short u16;

__device__ __forceinline__ u16 f2bf(float f) {
  unsigned int u = __float_as_uint(f);
  u += 0x7FFFu + ((u >> 16) & 1u);   // round-to-nearest-even
  return (u16)(u >> 16);
}
__device__ __forceinline__ float bf2f(u16 u) {
  return __uint_as_float(((unsigned int)u) << 16);
}
__device__ __forceinline__ s16x8 load8f_bf16(const float* p) {
  const f32x4* q = (const f32x4*)p;
  f32x4 a = q[0], b = q[1];
  s16x8 r;
  r[0]=(short)f2bf(a[0]); r[1]=(short)f2bf(a[1]); r[2]=(short)f2bf(a[2]); r[3]=(short)f2bf(a[3]);
  r[4]=(short)f2bf(b[0]); r[5]=(short)f2bf(b[1]); r[6]=(short)f2bf(b[2]); r[7]=(short)f2bf(b[3]);
  return r;
}

// ---------------------------------------------------------------------------
// K1: qkv = x @ w_in^T  (M=4096, K=128, N=384), grid (64 Mtiles, 3 groups)
// group g: 0=q, 1=k, 2=v.  q,k -> bf16 [h][i][d] + sumsq; v -> bf16 [h][d][i]
// ---------------------------------------------------------------------------
__global__ __launch_bounds__(256) void qkv_kernel(
    const float* __restrict__ x, const float* __restrict__ w_in,
    u16* __restrict__ Qb, u16* __restrict__ Kb, u16* __restrict__ Vtb,
    float* __restrict__ sq) {
  __shared__ float sqpart[128];
  const int tid = threadIdx.x;
  const int w = tid >> 6, lane = tid & 63, li = lane & 15, kg = lane >> 4;
  const int g = blockIdx.y;
  const int m0 = blockIdx.x * 64;
  if (tid < 128) sqpart[tid] = 0.f;
  __syncthreads();

  const int irow = m0 + w * 16;            // wave's first output row
  s16x8 ax[4];                             // A fragments: x[irow+li][kc*32+kg*8 ..+8]
#pragma unroll
  for (int kc = 0; kc < 4; ++kc)
    ax[kc] = load8f_bf16(x + (size_t)(irow + li) * 128 + kc * 32 + kg * 8);

  const float* W = w_in + (size_t)g * 128 * 128;
#pragma unroll
  for (int nt = 0; nt < 8; ++nt) {
    const int colrel = nt * 16 + li;       // this lane's output column (0..127)
    f32x4 acc = {0.f, 0.f, 0.f, 0.f};
#pragma unroll
    for (int kc = 0; kc < 4; ++kc) {
      s16x8 bw = load8f_bf16(W + (size_t)colrel * 128 + kc * 32 + kg * 8);
      acc = __builtin_amdgcn_mfma_f32_16x16x32_bf16(ax[kc], bw, acc, 0, 0, 0);
    }
    const int h = colrel >> 5, d = colrel & 31;
    const int r0 = irow + kg * 4;          // lane's 4 consecutive rows r0..r0+3
    if (g == 2) {
      u16x4 pv;
#pragma unroll
      for (int r = 0; r < 4; ++r) pv[r] = f2bf(acc[r]);
      *(u16x4*)(Vtb + ((size_t)(h * 32 + d) * 4096 + r0)) = pv;   // V^T[h][d][i]
    } else {
      float ss = acc[0]*acc[0] + acc[1]*acc[1] + acc[2]*acc[2] + acc[3]*acc[3];
      ss += __shfl_xor(ss, 16);
      ss += __shfl_xor(ss, 32);            // total over the wave's 16 rows
      if (lane < 16) atomicAdd(&sqpart[colrel], ss);
      u16* dst = (g == 0 ? Qb : Kb);
#pragma unroll
      for (int r = 0; r < 4; ++r)
        dst[((size_t)h * 4096 + r0 + r) * 32 + d] = f2bf(acc[r]);
    }
  }
  __syncthreads();
  if (g < 2 && tid < 128) atomicAdd(sq + g * 128 + tid, sqpart[tid]);
}

// ---------------------------------------------------------------------------
// K2: flash attention.  grid (64 q-blocks of 64 rows, 4 heads), 4 waves/block,
// 16 q-rows per wave, KV tiles of 64.  scale = SCALE/(||q_d||*||k_d||) folded
// into the Q fragment.  LDS row strides padded (2-way bank aliasing is free).
// ---------------------------------------------------------------------------
__global__ __launch_bounds__(256) void attn_kernel(
    const u16* __restrict__ Qb, const u16* __restrict__ Kb,
    const u16* __restrict__ Vtb, const float* __restrict__ sq,
    float* __restrict__ Oattn) {
  __shared__ __align__(16) u16 Klds[64][40];   // K[j][d]
  __shared__ __align__(16) u16 Vlds[32][72];   // V^T[d][j]
  __shared__ __align__(16) u16 Plds[4][16][72];// per-wave P[i][j], j in [0,64)
  const int tid = threadIdx.x;
  const int w = tid >> 6, lane = tid & 63, li = lane & 15, kg = lane >> 4;
  const int h = blockIdx.y;
  const int q0 = blockIdx.x * 64;

  // per-(h,d) scale for this lane's k-slice d = kg*8 + t
  float sc[8];
#pragma unroll
  for (int t = 0; t < 8; ++t) {
    int d = kg * 8 + t;
    float nq = fmaxf(sqrtf(sq[h * 32 + d]), 1e-8f);
    float nk = fmaxf(sqrtf(sq[128 + h * 32 + d]), 1e-8f);
    sc[t] = 10.f / (nq * nk);
  }
  // Q fragment (row = q0+w*16+li), scaled
  s16x8 aq;
  {
    const u16* qp = Qb + ((size_t)h * 4096 + q0 + w * 16 + li) * 32 + kg * 8;
    s16x8 qraw = *(const s16x8*)qp;
#pragma unroll
    for (int t = 0; t < 8; ++t) aq[t] = (short)f2bf(bf2f((u16)qraw[t]) * sc[t]);
  }

  float mrun[4] = {-1e30f, -1e30f, -1e30f, -1e30f};
  float sden[4] = {0.f, 0.f, 0.f, 0.f};
  f32x4 acc0 = {0,0,0,0}, acc1 = {0,0,0,0};
  const u16* Kh = Kb + (size_t)h * 4096 * 32;
  const u16* Vh = Vtb + (size_t)h * 32 * 4096;

  for (int jt = 0; jt < 64; ++jt) {
    const int j0 = jt * 64;
    // ---- stage K (64x32) and V^T (32x64) tiles, one 16B ld/st per thread
    {
      const u32x4* gk = (const u32x4*)(Kh + (size_t)j0 * 32);
      *(u32x4*)&Klds[tid >> 2][(tid & 3) * 8] = gk[tid];
      const u16* gv = Vh + (size_t)(tid >> 3) * 4096 + j0 + (tid & 7) * 8;
      *(u32x4*)&Vlds[tid >> 3][(tid & 7) * 8] = *(const u32x4*)gv;
    }
    __syncthreads();
    // ---- S = Q K^T  (4 j-subtiles of 16)
    f32x4 st[4];
#pragma unroll
    for (int jb = 0; jb < 4; ++jb) {
      s16x8 bk = *(const s16x8*)&Klds[jb * 16 + li][kg * 8];
      f32x4 z = {0, 0, 0, 0};
      st[jb] = __builtin_amdgcn_mfma_f32_16x16x32_bf16(aq, bk, z, 0, 0, 0);
    }
    // ---- online softmax (rows live at reg r, cols across lanes 0..15)
    float mx[4], al[4], rs[4], p[4][4];
#pragma unroll
    for (int r = 0; r < 4; ++r)
      mx[r] = fmaxf(fmaxf(st[0][r], st[1][r]), fmaxf(st[2][r], st[3][r]));
#pragma unroll
    for (int off = 1; off <= 8; off <<= 1) {
#pragma unroll
      for (int r = 0; r < 4; ++r) mx[r] = fmaxf(mx[r], __shfl_xor(mx[r], off));
    }
#pragma unroll
    for (int r = 0; r < 4; ++r) {
      float nm = fmaxf(mrun[r], mx[r]);
      al[r] = __expf(mrun[r] - nm);
      mrun[r] = nm;
    }
#pragma unroll
    for (int jb = 0; jb < 4; ++jb) {
#pragma unroll
      for (int r = 0; r < 4; ++r) p[jb][r] = __expf(st[jb][r] - mrun[r]);
    }
#pragma unroll
    for (int r = 0; r < 4; ++r) rs[r] = (p[0][r] + p[1][r]) + (p[2][r] + p[3][r]);
#pragma unroll
    for (int off = 1; off <= 8; off <<= 1) {
#pragma unroll
      for (int r = 0; r < 4; ++r) rs[r] += __shfl_xor(rs[r], off);
    }
#pragma unroll
    for (int r = 0; r < 4; ++r) {
      sden[r] = sden[r] * al[r] + rs[r];
      acc0[r] *= al[r];
      acc1[r] *= al[r];
    }
    // ---- P (C-layout) -> per-wave LDS -> A-fragment layout
#pragma unroll
    for (int jb = 0; jb < 4; ++jb) {
#pragma unroll
      for (int r = 0; r < 4; ++r)
        Plds[w][kg * 4 + r][jb * 16 + li] = f2bf(p[jb][r]);
    }
    // ---- O += P V  (2 k-chunks of 32 keys x 2 d-tiles of 16)
#pragma unroll
    for (int c = 0; c < 2; ++c) {
      s16x8 ap  = *(const s16x8*)&Plds[w][li][c * 32 + kg * 8];
      s16x8 bv0 = *(const s16x8*)&Vlds[li][c * 32 + kg * 8];
      s16x8 bv1 = *(const s16x8*)&Vlds[16 + li][c * 32 + kg * 8];
      acc0 = __builtin_amdgcn_mfma_f32_16x16x32_bf16(ap, bv0, acc0, 0, 0, 0);
      acc1 = __builtin_amdgcn_mfma_f32_16x16x32_bf16(ap, bv1, acc1, 0, 0, 0);
    }
    __syncthreads();
  }
  // ---- finalize: O[i][h*32+d] = acc/sden
#pragma unroll
  for (int r = 0; r < 4; ++r) {
    float inv = 1.f / sden[r];
    int i = q0 + w * 16 + kg * 4 + r;
    Oattn[(size_t)i * 128 + h * 32 + li]      = acc0[r] * inv;
    Oattn[(size_t)i * 128 + h * 32 + 16 + li] = acc1[r] * inv;
  }
}

// ---------------------------------------------------------------------------
// K3: out = Oattn @ w_out^T + b_out  (M=4096, K=128, N=128), grid (64, 2)
// ---------------------------------------------------------------------------
__global__ __launch_bounds__(256) void proj_kernel(
    const float* __restrict__ Oattn, const float* __restrict__ w_out,
    const float* __restrict__ b_out, float* __restrict__ out) {
  const int tid = threadIdx.x;
  const int w = tid >> 6, lane = tid & 63, li = lane & 15, kg = lane >> 4;
  const int i0 = blockIdx.x * 64 + w * 16;
  const int n0 = blockIdx.y * 64;
  s16x8 ao[4];
#pragma unroll
  for (int kc = 0; kc < 4; ++kc)
    ao[kc] = load8f_bf16(Oattn + (size_t)(i0 + li) * 128 + kc * 32 + kg * 8);
#pragma unroll
  for (int nt = 0; nt < 4; ++nt) {
    const int c = n0 + nt * 16 + li;
    f32x4 acc = {0, 0, 0, 0};
#pragma unroll
    for (int kc = 0; kc < 4; ++kc) {
      s16x8 bw = load8f_bf16(w_out + (size_t)c * 128 + kc * 32 + kg * 8);
      acc = __builtin_amdgcn_mfma_f32_16x16x32_bf16(ao[kc], bw, acc, 0, 0, 0);
    }
    const float bias = b_out[c];
#pragma unroll
    for (int r = 0; r < 4; ++r)
      out[(size_t)(i0 + kg * 4 + r) * 128 + c] = acc[r] + bias;
  }
}

// ---------------------------------------------------------------------------
extern "C" void kernel_launch(void* const* d_in, const int* in_sizes, int n_in,
                              void* d_out, int out_size, void* d_ws, size_t ws_size,
                              hipStream_t stream) {
  const float* x     = (const float*)d_in[0];
  const float* w_in  = (const float*)d_in[1];
  const float* w_out = (const float*)d_in[2];
  const float* b_out = (const float*)d_in[3];
  float* out = (float*)d_out;

  char* ws = (char*)d_ws;
  float* sq  = (float*)ws;                              // [2][128] f32 sumsq(q), sumsq(k)
  u16*   Qb  = (u16*)(ws + 1024);                       // [4][4096][32] bf16
  u16*   Kb  = (u16*)(ws + 1024 + 1 * 1048576);         // [4][4096][32] bf16
  u16*   Vtb = (u16*)(ws + 1024 + 2 * 1048576);         // [4][32][4096] bf16 (V^T)
  float* Oat = (float*)(ws + 1024 + 3 * 1048576);       // [4096][128] f32

  hipMemsetAsync(sq, 0, 1024, stream);
  qkv_kernel <<<dim3(64, 3), 256, 0, stream>>>(x, w_in, Qb, Kb, Vtb, sq);
  attn_kernel<<<dim3(64, 4), 256, 0, stream>>>(Qb, Kb, Vtb, sq, Oat);
  proj_kernel<<<dim3(64, 2), 256, 0, stream>>>(Oat, w_out, b_out, out);
}

// Round 5
// 129.724 us; speedup vs baseline: 1.2781x; 1.2781x over previous
//
#include <hip/hip_runtime.h>
#include <hip/hip_bf16.h>

// Attention_6828998000803 on MI355X (gfx950)
// H=W=64, C=128, HEADS=4, DIM_HEAD=32, HW=4096, SCALE=10, EPS=1e-8
//
// memset(O,denom) -> qkv GEMM (writes Q,K,V^T bf16 + per-block sumsq partials)
// -> flash attention (linear softmax: no max needed since |sim|<~1.2;
//    split-KV x4, barrier-free main loop, K/V direct from L2, atomicAdd combine)
// -> output projection (divide by denom, bf16 MFMA, + bias)

typedef float  f32x4 __attribute__((ext_vector_type(4)));
typedef short  s16x8 __attribute__((ext_vector_type(8)));
typedef unsigned short u16x4 __attribute__((ext_vector_type(4)));
typedef unsigned short u16;

__device__ __forceinline__ u16 f2bf(float f) {
  unsigned int u = __float_as_uint(f);
  u += 0x7FFFu + ((u >> 16) & 1u);   // round-to-nearest-even
  return (u16)(u >> 16);
}
__device__ __forceinline__ float bf2f(u16 u) {
  return __uint_as_float(((unsigned int)u) << 16);
}
__device__ __forceinline__ s16x8 load8f_bf16(const float* p) {
  const f32x4* q = (const f32x4*)p;
  f32x4 a = q[0], b = q[1];
  s16x8 r;
  r[0]=(short)f2bf(a[0]); r[1]=(short)f2bf(a[1]); r[2]=(short)f2bf(a[2]); r[3]=(short)f2bf(a[3]);
  r[4]=(short)f2bf(b[0]); r[5]=(short)f2bf(b[1]); r[6]=(short)f2bf(b[2]); r[7]=(short)f2bf(b[3]);
  return r;
}

// ---------------------------------------------------------------------------
// K1: qkv = x @ w_in^T  (M=4096, K=128, N=384), grid (128 Mtiles of 32, 3 g)
// g: 0=q, 1=k, 2=v.  q,k -> bf16 [h][i][d] + per-Mblock sumsq partials;
// v -> bf16 [h][d][i] (transposed)
// ---------------------------------------------------------------------------
__global__ __launch_bounds__(128) void qkv_kernel(
    const float* __restrict__ x, const float* __restrict__ w_in,
    u16* __restrict__ Qb, u16* __restrict__ Kb, u16* __restrict__ Vtb,
    float* __restrict__ part_sq) {
  __shared__ float sqpart[2][128];
  const int tid = threadIdx.x;
  const int w = tid >> 6, lane = tid & 63, li = lane & 15, kg = lane >> 4;
  const int g = blockIdx.y;
  const int mb = blockIdx.x;
  const int irow = mb * 32 + w * 16;

  s16x8 ax[4];
#pragma unroll
  for (int kc = 0; kc < 4; ++kc)
    ax[kc] = load8f_bf16(x + (size_t)(irow + li) * 128 + kc * 32 + kg * 8);

  const float* W = w_in + (size_t)g * 128 * 128;
#pragma unroll
  for (int nt = 0; nt < 8; ++nt) {
    const int colrel = nt * 16 + li;
    f32x4 acc = {0.f, 0.f, 0.f, 0.f};
#pragma unroll
    for (int kc = 0; kc < 4; ++kc) {
      s16x8 bw = load8f_bf16(W + (size_t)colrel * 128 + kc * 32 + kg * 8);
      acc = __builtin_amdgcn_mfma_f32_16x16x32_bf16(ax[kc], bw, acc, 0, 0, 0);
    }
    const int h = colrel >> 5, d = colrel & 31;
    const int r0 = irow + kg * 4;
    if (g == 2) {
      u16x4 pv;
#pragma unroll
      for (int r = 0; r < 4; ++r) pv[r] = f2bf(acc[r]);
      *(u16x4*)(Vtb + ((size_t)(h * 32 + d) * 4096 + r0)) = pv;   // V^T[h][d][i]
    } else {
      float ss = acc[0]*acc[0] + acc[1]*acc[1] + acc[2]*acc[2] + acc[3]*acc[3];
      ss += __shfl_xor(ss, 16);
      ss += __shfl_xor(ss, 32);            // sum over this wave's 16 rows
      if (lane < 16) sqpart[w][colrel] = ss;
      u16* dst = (g == 0 ? Qb : Kb);
#pragma unroll
      for (int r = 0; r < 4; ++r)
        dst[((size_t)h * 4096 + r0 + r) * 32 + d] = f2bf(acc[r]);
    }
  }
  __syncthreads();
  if (g < 2 && tid < 128)
    part_sq[((size_t)g * 128 + tid) * 128 + mb] = sqpart[0][tid] + sqpart[1][tid];
}

// ---------------------------------------------------------------------------
// K2: flash attention, linear softmax (no max: |sim| <= ~1.2).
// grid (64 q-blocks, 4 heads, 4 KV-chunks of 1024), 4 waves/block, 16 q-rows
// per wave.  K/V fragments read directly from global (L2-resident, 256KB/head)
// with register prefetch; NO barriers in the main loop.  Swapped QK^T
// (mfma(K,Q)) puts each P-row in one lane -> b64 P writes into XOR-swizzled
// per-wave LDS slab (128B rows).  Partial O/denom combined via atomicAdd.
// ---------------------------------------------------------------------------
__global__ __launch_bounds__(256, 4) void attn_kernel(
    const u16* __restrict__ Qb, const u16* __restrict__ Kb,
    const u16* __restrict__ Vtb, const float* __restrict__ part_sq,
    float* __restrict__ Oat, float* __restrict__ denom) {
  __shared__ float scs[32];
  __shared__ __align__(16) u16 Plds[4][16][64];   // per-wave P[i][j], 128B rows
  const int tid = threadIdx.x;
  const int w = tid >> 6, lane = tid & 63, li = lane & 15, kg = lane >> 4;
  const int h = blockIdx.y;
  const int q0 = blockIdx.x * 64;
  const int s  = blockIdx.z;

  // --- prologue: reduce per-Mblock sumsq partials -> scale table (wave 0)
  if (w == 0) {
    const int kind = lane >> 5, d = lane & 31;
    const f32x4* p4 = (const f32x4*)(part_sq + (size_t)(kind * 128 + h * 32 + d) * 128);
    float sum = 0.f;
#pragma unroll
    for (int m = 0; m < 32; ++m) { f32x4 v = p4[m]; sum += (v[0]+v[1]) + (v[2]+v[3]); }
    float n = fmaxf(sqrtf(sum), 1e-8f);
    float other = __shfl_xor(n, 32);         // pair q-norm with k-norm, same d
    if (lane < 32) scs[lane] = 10.f / (n * other);
  }
  __syncthreads();

  // --- Q fragment for this wave's 16 rows, scale folded in
  s16x8 aq;
  {
    const u16* qp = Qb + ((size_t)h * 4096 + q0 + w * 16 + li) * 32 + kg * 8;
    s16x8 qr = *(const s16x8*)qp;
#pragma unroll
    for (int t = 0; t < 8; ++t) aq[t] = (short)f2bf(bf2f((u16)qr[t]) * scs[kg * 8 + t]);
  }

  const u16* Kh = Kb  + (size_t)h * 4096 * 32;
  const u16* Vh = Vtb + (size_t)h * 32 * 4096;
  char* Pw = (char*)&Plds[w][0][0];
  const int pbase = li * 128;
  const int psw   = (li & 7) << 4;           // XOR bank swizzle

  f32x4 acc0 = {0,0,0,0}, acc1 = {0,0,0,0};
  float sden = 0.f;

  // preload tile 0
  s16x8 kf[4], vf[4];
  {
    const int j0 = s * 1024;
#pragma unroll
    for (int jb = 0; jb < 4; ++jb)
      kf[jb] = *(const s16x8*)(Kh + (size_t)(j0 + jb * 16 + li) * 32 + kg * 8);
#pragma unroll
    for (int c = 0; c < 2; ++c)
#pragma unroll
      for (int hf = 0; hf < 2; ++hf)
        vf[c * 2 + hf] = *(const s16x8*)(Vh + (size_t)(li + hf * 16) * 4096 + j0 + c * 32 + kg * 8);
  }

  for (int jt = 0; jt < 16; ++jt) {
    // prefetch next tile (wraps at jt=15; loaded values unused then)
    const int jn = (s * 1024 + (jt + 1) * 64) & 4095;
    s16x8 kn[4], vn[4];
#pragma unroll
    for (int jb = 0; jb < 4; ++jb)
      kn[jb] = *(const s16x8*)(Kh + (size_t)(jn + jb * 16 + li) * 32 + kg * 8);
#pragma unroll
    for (int c = 0; c < 2; ++c)
#pragma unroll
      for (int hf = 0; hf < 2; ++hf)
        vn[c * 2 + hf] = *(const s16x8*)(Vh + (size_t)(li + hf * 16) * 4096 + jn + c * 32 + kg * 8);

    // S^T = K Q^T : lane holds S[j = kg*4+r (+16jb)][i = li]
    f32x4 st[4];
#pragma unroll
    for (int jb = 0; jb < 4; ++jb) {
      f32x4 z = {0, 0, 0, 0};
      st[jb] = __builtin_amdgcn_mfma_f32_16x16x32_bf16(kf[jb], aq, z, 0, 0, 0);
    }
    // exp (no max), denominator accumulate, pack P -> LDS (b64, swizzled)
#pragma unroll
    for (int jb = 0; jb < 4; ++jb) {
      float p0 = __expf(st[jb][0]), p1 = __expf(st[jb][1]);
      float p2 = __expf(st[jb][2]), p3 = __expf(st[jb][3]);
      sden += (p0 + p1) + (p2 + p3);
      uint2 pk;
      pk.x = (unsigned)f2bf(p0) | ((unsigned)f2bf(p1) << 16);
      pk.y = (unsigned)f2bf(p2) | ((unsigned)f2bf(p3) << 16);
      *(uint2*)(Pw + pbase + ((jb * 32 + kg * 8) ^ psw)) = pk;
    }
    // O += P V  (wave-internal LDS round-trip, no barrier)
#pragma unroll
    for (int c = 0; c < 2; ++c) {
      s16x8 ap = *(const s16x8*)(Pw + pbase + ((c * 64 + kg * 16) ^ psw));
      acc0 = __builtin_amdgcn_mfma_f32_16x16x32_bf16(ap, vf[c * 2 + 0], acc0, 0, 0, 0);
      acc1 = __builtin_amdgcn_mfma_f32_16x16x32_bf16(ap, vf[c * 2 + 1], acc1, 0, 0, 0);
    }
#pragma unroll
    for (int jb = 0; jb < 4; ++jb) kf[jb] = kn[jb];
#pragma unroll
    for (int c = 0; c < 4; ++c) vf[c] = vn[c];
  }

  // --- combine: O and denom are additive across chunks (linear softmax)
#pragma unroll
  for (int r = 0; r < 4; ++r) {
    const int i = q0 + w * 16 + kg * 4 + r;
    atomicAdd(Oat + (size_t)i * 128 + h * 32 + li,      acc0[r]);
    atomicAdd(Oat + (size_t)i * 128 + h * 32 + 16 + li, acc1[r]);
  }
  sden += __shfl_xor(sden, 16);
  sden += __shfl_xor(sden, 32);
  if (lane < 16) atomicAdd(denom + (size_t)h * 4096 + q0 + w * 16 + li, sden);
}

// ---------------------------------------------------------------------------
// K3: out = (Oat/denom) @ w_out^T + b_out  (M=4096, K=128, N=128)
// grid (128 Mtiles of 32, 2 N-halves), 128 threads
// ---------------------------------------------------------------------------
__global__ __launch_bounds__(128) void proj_kernel(
    const float* __restrict__ Oat, const float* __restrict__ denom,
    const float* __restrict__ w_out, const float* __restrict__ b_out,
    float* __restrict__ out) {
  const int tid = threadIdx.x;
  const int w = tid >> 6, lane = tid & 63, li = lane & 15, kg = lane >> 4;
  const int i0 = blockIdx.x * 32 + w * 16;
  const int n0 = blockIdx.y * 64;
  const int i = i0 + li;

  s16x8 ao[4];
#pragma unroll
  for (int kc = 0; kc < 4; ++kc) {
    const float inv = 1.f / denom[(size_t)kc * 4096 + i];
    const f32x4* p = (const f32x4*)(Oat + (size_t)i * 128 + kc * 32 + kg * 8);
    f32x4 a = p[0], b = p[1];
    s16x8 r;
    r[0]=(short)f2bf(a[0]*inv); r[1]=(short)f2bf(a[1]*inv);
    r[2]=(short)f2bf(a[2]*inv); r[3]=(short)f2bf(a[3]*inv);
    r[4]=(short)f2bf(b[0]*inv); r[5]=(short)f2bf(b[1]*inv);
    r[6]=(short)f2bf(b[2]*inv); r[7]=(short)f2bf(b[3]*inv);
    ao[kc] = r;
  }
#pragma unroll
  for (int nt = 0; nt < 4; ++nt) {
    const int c = n0 + nt * 16 + li;
    f32x4 acc = {0, 0, 0, 0};
#pragma unroll
    for (int kc = 0; kc < 4; ++kc) {
      s16x8 bw = load8f_bf16(w_out + (size_t)c * 128 + kc * 32 + kg * 8);
      acc = __builtin_amdgcn_mfma_f32_16x16x32_bf16(ao[kc], bw, acc, 0, 0, 0);
    }
    const float bias = b_out[c];
#pragma unroll
    for (int r = 0; r < 4; ++r)
      out[(size_t)(i0 + kg * 4 + r) * 128 + c] = acc[r] + bias;
  }
}

// ---------------------------------------------------------------------------
extern "C" void kernel_launch(void* const* d_in, const int* in_sizes, int n_in,
                              void* d_out, int out_size, void* d_ws, size_t ws_size,
                              hipStream_t stream) {
  const float* x     = (const float*)d_in[0];
  const float* w_in  = (const float*)d_in[1];
  const float* w_out = (const float*)d_in[2];
  const float* b_out = (const float*)d_in[3];
  float* out = (float*)d_out;

  char* ws = (char*)d_ws;
  float* Oat     = (float*)ws;                          // [4096][128] f32 (2MB)
  float* denom   = (float*)(ws + 2097152);              // [4][4096] f32 (64KB)
  float* part_sq = (float*)(ws + 2097152 + 65536);      // [256][128] f32 (128KB)
  u16*   Qb  = (u16*)(ws + 2097152 + 65536 + 131072);               // [4][4096][32]
  u16*   Kb  = (u16*)(ws + 2097152 + 65536 + 131072 + 1048576);     // [4][4096][32]
  u16*   Vtb = (u16*)(ws + 2097152 + 65536 + 131072 + 2 * 1048576); // [4][32][4096]

  hipMemsetAsync(Oat, 0, 2097152 + 65536, stream);      // O + denom accumulators
  qkv_kernel <<<dim3(128, 3),    128, 0, stream>>>(x, w_in, Qb, Kb, Vtb, part_sq);
  attn_kernel<<<dim3(64, 4, 4),  256, 0, stream>>>(Qb, Kb, Vtb, part_sq, Oat, denom);
  proj_kernel<<<dim3(128, 2),    128, 0, stream>>>(Oat, denom, w_out, b_out, out);
}